// Round 2
// baseline (466.006 us; speedup 1.0000x reference)
//
#include <hip/hip_runtime.h>
#include <cfloat>

// Problem constants (fixed by setup_inputs):
//   z:   [8,16,16,16,32] fp32  -> N = 32768 rows, c = 32
//   emb: [8192, 32] fp32       -> K = 8192 codes
// Outputs (concatenated fp32 in d_out):
//   [0, 1048576)            quantized_st  (== emb[idx], forward)
//   [1048576]               vq_loss        (scalar)
//   [1048577]               commitment_loss (scalar, same value fwd)
//   [1048578, 1081346)      idx as float   (32768)

#define NROW   32768
#define KCODES 8192
#define CDIM   32
#define NCHUNK 8
#define KCHUNK (KCODES / NCHUNK)  // 1024

#define OUT_Q    0
#define OUT_LOSS 1048576
#define OUT_IDX  1048578

// ---------------------------------------------------------------------------
// Kernel 1: enorm[k] = ||emb_k||^2 ; also zero the two loss accumulators.
// ---------------------------------------------------------------------------
__global__ __launch_bounds__(256) void vq_enorm_kernel(
    const float* __restrict__ emb, float* __restrict__ enorm,
    float* __restrict__ out) {
  int k = blockIdx.x * 256 + threadIdx.x;
  if (k < KCODES) {
    const float4* e4 = (const float4*)(emb + (size_t)k * CDIM);
    float s = 0.f;
#pragma unroll
    for (int j = 0; j < CDIM / 4; ++j) {
      float4 v = e4[j];
      s += v.x * v.x + v.y * v.y + v.z * v.z + v.w * v.w;
    }
    enorm[k] = s;
  }
  if (blockIdx.x == 0 && threadIdx.x < 2) out[OUT_LOSS + threadIdx.x] = 0.f;
}

// ---------------------------------------------------------------------------
// Kernel 2: per (row, K-chunk) partial argmin.
// CRITICAL numerics: replicate the reference's fp32 quantization —
//   s = fl32( fl32(znorm - 2*dot) + enorm[k] )
// znorm ~ 32 quantizes s to ulp(32)=3.8e-6, creating ties the reference
// breaks by first index; matching the grid is required for idx agreement.
// Codes are wave-uniform -> emb/enorm reads compile to scalar loads.
// grid = (NROW/256, NCHUNK)
// ---------------------------------------------------------------------------
__global__ __launch_bounds__(256) void vq_argmin_kernel(
    const float* __restrict__ z, const float* __restrict__ emb,
    const float* __restrict__ enorm,
    float* __restrict__ pval, int* __restrict__ pidx) {
  const int r = blockIdx.x * 256 + threadIdx.x;
  const int c = blockIdx.y;

  float zr[CDIM];
  const float4* z4 = (const float4*)(z + (size_t)r * CDIM);
#pragma unroll
  for (int j = 0; j < CDIM / 4; ++j) {
    float4 v = z4[j];
    zr[4 * j + 0] = v.x;
    zr[4 * j + 1] = v.y;
    zr[4 * j + 2] = v.z;
    zr[4 * j + 3] = v.w;
  }
  float znorm = 0.f;
#pragma unroll
  for (int j = 0; j < CDIM; ++j) znorm = fmaf(zr[j], zr[j], znorm);

  const int kbeg = c * KCHUNK;
  float best = FLT_MAX;
  int bidx = kbeg;
  for (int k = kbeg; k < kbeg + KCHUNK; ++k) {
    const float* __restrict__ ek = emb + (size_t)k * CDIM;  // wave-uniform
    float dot = 0.f;
#pragma unroll
    for (int j = 0; j < CDIM; ++j) dot = fmaf(zr[j], ek[j], dot);
    // Match reference rounding sequence: (znorm - 2*dot) then + enorm.
    float t = znorm - 2.f * dot;   // 2*dot is exact; one rounding here
    float s = t + enorm[k];        // second rounding
    if (s < best) { best = s; bidx = k; }  // strict < : first-min tie-break
  }
  pval[(size_t)c * NROW + r] = best;
  pidx[(size_t)c * NROW + r] = bidx;
}

// ---------------------------------------------------------------------------
// Kernel 3: reduce the NCHUNK partials per row (ascending chunk order keeps
// jnp.argmin first-index tie-break), gather emb[idx] -> out, idx -> out,
// accumulate loss = mean((z - q)^2) via one atomic per wave.
// ---------------------------------------------------------------------------
__global__ __launch_bounds__(256) void vq_finalize_kernel(
    const float* __restrict__ z, const float* __restrict__ emb,
    const float* __restrict__ pval, const int* __restrict__ pidx,
    float* __restrict__ out) {
  const int r = blockIdx.x * 256 + threadIdx.x;

  float best = FLT_MAX;
  int bidx = 0;
#pragma unroll
  for (int c = 0; c < NCHUNK; ++c) {
    float v = pval[(size_t)c * NROW + r];
    int i = pidx[(size_t)c * NROW + r];
    if (v < best) { best = v; bidx = i; }  // ascending c: first-min kept
  }

  const float4* q4 = (const float4*)(emb + (size_t)bidx * CDIM);
  const float4* z4 = (const float4*)(z + (size_t)r * CDIM);
  float4* o4 = (float4*)(out + OUT_Q + (size_t)r * CDIM);

  float lsum = 0.f;
#pragma unroll
  for (int j = 0; j < CDIM / 4; ++j) {
    float4 q = q4[j];
    float4 zz = z4[j];
    float dx = zz.x - q.x, dy = zz.y - q.y, dz = zz.z - q.z, dw = zz.w - q.w;
    lsum += dx * dx + dy * dy + dz * dz + dw * dw;
    o4[j] = q;  // forward straight-through output == quantized
  }
  out[OUT_IDX + r] = (float)bidx;

  // wave64 reduction, then one atomic per wave per loss slot
#pragma unroll
  for (int off = 32; off > 0; off >>= 1) lsum += __shfl_down(lsum, off, 64);
  if ((threadIdx.x & 63) == 0) {
    float v = lsum * (1.0f / (float)(NROW * CDIM));
    atomicAdd(out + OUT_LOSS + 0, v);  // vq_loss
    atomicAdd(out + OUT_LOSS + 1, v);  // commitment_loss (same fwd value)
  }
}

// ---------------------------------------------------------------------------
extern "C" void kernel_launch(void* const* d_in, const int* in_sizes, int n_in,
                              void* d_out, int out_size, void* d_ws,
                              size_t ws_size, hipStream_t stream) {
  const float* z = (const float*)d_in[0];    // 1048576 elems
  const float* emb = (const float*)d_in[1];  // 262144 elems
  float* out = (float*)d_out;

  // ws layout (floats): enorm[8192] | pval[NCHUNK*NROW] | pidx[NCHUNK*NROW]
  float* enorm = (float*)d_ws;
  float* pval = enorm + KCODES;
  int* pidx = (int*)(pval + (size_t)NCHUNK * NROW);

  vq_enorm_kernel<<<KCODES / 256, 256, 0, stream>>>(emb, enorm, out);
  vq_argmin_kernel<<<dim3(NROW / 256, NCHUNK), 256, 0, stream>>>(
      z, emb, enorm, pval, pidx);
  vq_finalize_kernel<<<NROW / 256, 256, 0, stream>>>(z, emb, pval, pidx, out);
}

// Round 3
// 377.868 us; speedup vs baseline: 1.2333x; 1.2333x over previous
//
#include <hip/hip_runtime.h>
#include <cfloat>
#include <stdint.h>

// z: [32768, 32] fp32 rows; emb: [8192, 32] fp32 codes.
// Outputs (fp32, concat): quantized[1048576] | vq_loss | commit_loss | idx[32768]
#define NROW   32768
#define KCODES 8192
#define CDIM   32
#define NCHUNK 32
#define KCHUNK (KCODES / NCHUNK)  // 256 codes per block

#define OUT_Q    0
#define OUT_LOSS 1048576
#define OUT_IDX  1048578

// ---------------------------------------------------------------------------
// Kernel 1: enorm[k] = ||emb_k||^2 ; init per-row argmin keys; zero losses.
// grid = NROW/256 blocks (32768 threads).
// ---------------------------------------------------------------------------
__global__ __launch_bounds__(256) void vq_prep_kernel(
    const float* __restrict__ emb, float* __restrict__ enorm,
    unsigned long long* __restrict__ key, float* __restrict__ out) {
  int t = blockIdx.x * 256 + threadIdx.x;
  if (t < KCODES) {
    const float4* e4 = (const float4*)(emb + (size_t)t * CDIM);
    float s = 0.f;
#pragma unroll
    for (int j = 0; j < CDIM / 4; ++j) {
      float4 v = e4[j];
      s += v.x * v.x + v.y * v.y + v.z * v.z + v.w * v.w;
    }
    enorm[t] = s;
  }
  key[t] = 0xFFFFFFFFFFFFFFFFull;  // t < NROW always
  if (t < 2) out[OUT_LOSS + t] = 0.f;
}

// ---------------------------------------------------------------------------
// Kernel 2: per (row, K-chunk) argmin of s = fl(fl(znorm - 2*dot) + enorm[k])
// (reference fp32 rounding grid — required for idx tie agreement).
// z row pinned in VGPRs via asm (R2 showed compiler re-loads it otherwise:
// VGPR_Count was 20, k-loop was L1-load-bound at 403us).
// Result folded per-row via atomicMin on key = (f32bits(s)<<13)|k :
// s>0 so IEEE bits are order-monotone; low bits give first-index tie-break.
// grid = (NROW/256, NCHUNK)
// ---------------------------------------------------------------------------
__global__ __launch_bounds__(256, 8) void vq_argmin_kernel(
    const float* __restrict__ z, const float* __restrict__ emb,
    const float* __restrict__ enorm, unsigned long long* __restrict__ key) {
  const int r = blockIdx.x * 256 + threadIdx.x;
  const int c = blockIdx.y;

  float zr[CDIM];
  const float4* z4 = (const float4*)(z + (size_t)r * CDIM);
#pragma unroll
  for (int j = 0; j < CDIM / 4; ++j) {
    float4 v = z4[j];
    zr[4 * j + 0] = v.x;
    zr[4 * j + 1] = v.y;
    zr[4 * j + 2] = v.z;
    zr[4 * j + 3] = v.w;
  }
  // Pin all 32 values in VGPRs: asm may modify them, so the compiler cannot
  // re-materialize the global loads inside the k-loop.
  asm volatile("" : "+v"(zr[0]), "+v"(zr[1]), "+v"(zr[2]), "+v"(zr[3]),
                    "+v"(zr[4]), "+v"(zr[5]), "+v"(zr[6]), "+v"(zr[7]),
                    "+v"(zr[8]), "+v"(zr[9]), "+v"(zr[10]), "+v"(zr[11]),
                    "+v"(zr[12]), "+v"(zr[13]), "+v"(zr[14]), "+v"(zr[15]));
  asm volatile("" : "+v"(zr[16]), "+v"(zr[17]), "+v"(zr[18]), "+v"(zr[19]),
                    "+v"(zr[20]), "+v"(zr[21]), "+v"(zr[22]), "+v"(zr[23]),
                    "+v"(zr[24]), "+v"(zr[25]), "+v"(zr[26]), "+v"(zr[27]),
                    "+v"(zr[28]), "+v"(zr[29]), "+v"(zr[30]), "+v"(zr[31]));

  float znorm = 0.f;
#pragma unroll
  for (int j = 0; j < CDIM; ++j) znorm = fmaf(zr[j], zr[j], znorm);

  const int kbeg = c * KCHUNK;
  float best = FLT_MAX;
  int bidx = kbeg;
  for (int k = kbeg; k < kbeg + KCHUNK; ++k) {
    const float* __restrict__ ek = emb + (size_t)k * CDIM;  // wave-uniform
    float dot = 0.f;
#pragma unroll
    for (int j = 0; j < CDIM; ++j) dot = fmaf(zr[j], ek[j], dot);
    float t = fmaf(-2.f, dot, znorm);  // fl(znorm - 2*dot), one rounding
    float s = t + enorm[k];            // second rounding (reference grid)
    if (s < best) { best = s; bidx = k; }  // strict <: first-min tie-break
  }

  unsigned long long kk =
      ((unsigned long long)__float_as_uint(best) << 13) | (unsigned long long)bidx;
  atomicMin(&key[r], kk);
}

// ---------------------------------------------------------------------------
// Kernel 3: idx = key[r] low bits; gather emb[idx] -> out; idx -> out;
// loss = mean((z - q)^2) via wave reduce + one atomic per wave.
// ---------------------------------------------------------------------------
__global__ __launch_bounds__(256) void vq_finalize_kernel(
    const float* __restrict__ z, const float* __restrict__ emb,
    const unsigned long long* __restrict__ key, float* __restrict__ out) {
  const int r = blockIdx.x * 256 + threadIdx.x;
  const int bidx = (int)(key[r] & (unsigned long long)(KCODES - 1));

  const float4* q4 = (const float4*)(emb + (size_t)bidx * CDIM);
  const float4* z4 = (const float4*)(z + (size_t)r * CDIM);
  float4* o4 = (float4*)(out + OUT_Q + (size_t)r * CDIM);

  float lsum = 0.f;
#pragma unroll
  for (int j = 0; j < CDIM / 4; ++j) {
    float4 q = q4[j];
    float4 zz = z4[j];
    float dx = zz.x - q.x, dy = zz.y - q.y, dz = zz.z - q.z, dw = zz.w - q.w;
    lsum += dx * dx + dy * dy + dz * dz + dw * dw;
    o4[j] = q;  // forward straight-through output == quantized
  }
  out[OUT_IDX + r] = (float)bidx;

#pragma unroll
  for (int off = 32; off > 0; off >>= 1) lsum += __shfl_down(lsum, off, 64);
  if ((threadIdx.x & 63) == 0) {
    float v = lsum * (1.0f / (float)(NROW * CDIM));
    atomicAdd(out + OUT_LOSS + 0, v);  // vq_loss
    atomicAdd(out + OUT_LOSS + 1, v);  // commitment_loss (same fwd value)
  }
}

// ---------------------------------------------------------------------------
extern "C" void kernel_launch(void* const* d_in, const int* in_sizes, int n_in,
                              void* d_out, int out_size, void* d_ws,
                              size_t ws_size, hipStream_t stream) {
  const float* z = (const float*)d_in[0];    // 1048576 elems
  const float* emb = (const float*)d_in[1];  // 262144 elems
  float* out = (float*)d_out;

  // ws layout: enorm[8192] f32 (32KB) | key[32768] u64 (256KB)
  float* enorm = (float*)d_ws;
  unsigned long long* key = (unsigned long long*)(enorm + KCODES);

  vq_prep_kernel<<<NROW / 256, 256, 0, stream>>>(emb, enorm, key, out);
  vq_argmin_kernel<<<dim3(NROW / 256, NCHUNK), 256, 0, stream>>>(
      z, emb, enorm, key);
  vq_finalize_kernel<<<NROW / 256, 256, 0, stream>>>(z, emb, key, out);
}

// Round 4
// 292.038 us; speedup vs baseline: 1.5957x; 1.2939x over previous
//
#include <hip/hip_runtime.h>
#include <cfloat>
#include <stdint.h>

// z: [32768, 32] fp32 rows; emb: [8192, 32] fp32 codes.
// Outputs (fp32, concat): quantized[1048576] | vq_loss | commit_loss | idx[32768]
#define NROW   32768
#define KCODES 8192
#define CDIM   32
#define NCHUNK 32
#define KCHUNK (KCODES / NCHUNK)  // 256 codes staged in LDS per block
#define RPT    2                  // rows per thread
#define ROWS_PER_BLOCK (256 * RPT)  // 512

#define OUT_Q    0
#define OUT_LOSS 1048576
#define OUT_IDX  1048578

// ---------------------------------------------------------------------------
// Kernel 1: enorm[k] = ||emb_k||^2 ; init per-row argmin keys; zero losses.
// ---------------------------------------------------------------------------
__global__ __launch_bounds__(256) void vq_prep_kernel(
    const float* __restrict__ emb, float* __restrict__ enorm,
    unsigned long long* __restrict__ key, float* __restrict__ out) {
  int t = blockIdx.x * 256 + threadIdx.x;
  if (t < KCODES) {
    const float4* e4 = (const float4*)(emb + (size_t)t * CDIM);
    float s = 0.f;
#pragma unroll
    for (int j = 0; j < CDIM / 4; ++j) {
      float4 v = e4[j];
      s += v.x * v.x + v.y * v.y + v.z * v.z + v.w * v.w;
    }
    enorm[t] = s;
  }
  key[t] = 0xFFFFFFFFFFFFFFFFull;  // t < NROW always
  if (t < 2) out[OUT_LOSS + t] = 0.f;
}

// ---------------------------------------------------------------------------
// Kernel 2: per (row-pair, K-chunk) argmin.
// emb chunk + enorm staged in LDS (uniform-address ds_read broadcast in the
// k-loop); 2 z rows per thread pinned in VGPRs via asm. Numerics identical
// to the R3-passing chain: s = fl(fl(znorm - 2*dot) + enorm[k]), dot =
// ascending-j sequential fmaf. Per-row fold via atomicMin on
// key = (f32bits(s)<<13)|k  (s>0 -> IEEE-monotone; low bits = first-index
// tie-break).  grid = (NROW/512, NCHUNK).
// ---------------------------------------------------------------------------
__global__ __launch_bounds__(256, 4) void vq_argmin_kernel(
    const float* __restrict__ z, const float* __restrict__ emb,
    const float* __restrict__ enorm, unsigned long long* __restrict__ key) {
  __shared__ float se[KCHUNK * CDIM];  // 32 KB
  __shared__ float sn[KCHUNK];         // 1 KB

  const int t = threadIdx.x;
  const int kbeg = blockIdx.y * KCHUNK;
  const int r0 = blockIdx.x * ROWS_PER_BLOCK + t;
  const int r1 = r0 + 256;

  // ---- stage emb chunk (flat, coalesced) + enorm into LDS ----
  {
    const float4* g4 = (const float4*)(emb + (size_t)kbeg * CDIM);
    float4* s4 = (float4*)se;
#pragma unroll
    for (int i = 0; i < (KCHUNK * CDIM) / (4 * 256); ++i)  // 8 iters
      s4[i * 256 + t] = g4[i * 256 + t];
    sn[t] = enorm[kbeg + t];
  }

  // ---- load the two z rows into registers and pin them ----
  float za[CDIM], zb[CDIM];
  {
    const float4* z4a = (const float4*)(z + (size_t)r0 * CDIM);
    const float4* z4b = (const float4*)(z + (size_t)r1 * CDIM);
#pragma unroll
    for (int j = 0; j < CDIM / 4; ++j) {
      float4 va = z4a[j];
      za[4 * j + 0] = va.x; za[4 * j + 1] = va.y;
      za[4 * j + 2] = va.z; za[4 * j + 3] = va.w;
      float4 vb = z4b[j];
      zb[4 * j + 0] = vb.x; zb[4 * j + 1] = vb.y;
      zb[4 * j + 2] = vb.z; zb[4 * j + 3] = vb.w;
    }
  }
  asm volatile("" : "+v"(za[0]), "+v"(za[1]), "+v"(za[2]), "+v"(za[3]),
                    "+v"(za[4]), "+v"(za[5]), "+v"(za[6]), "+v"(za[7]),
                    "+v"(za[8]), "+v"(za[9]), "+v"(za[10]), "+v"(za[11]),
                    "+v"(za[12]), "+v"(za[13]), "+v"(za[14]), "+v"(za[15]));
  asm volatile("" : "+v"(za[16]), "+v"(za[17]), "+v"(za[18]), "+v"(za[19]),
                    "+v"(za[20]), "+v"(za[21]), "+v"(za[22]), "+v"(za[23]),
                    "+v"(za[24]), "+v"(za[25]), "+v"(za[26]), "+v"(za[27]),
                    "+v"(za[28]), "+v"(za[29]), "+v"(za[30]), "+v"(za[31]));
  asm volatile("" : "+v"(zb[0]), "+v"(zb[1]), "+v"(zb[2]), "+v"(zb[3]),
                    "+v"(zb[4]), "+v"(zb[5]), "+v"(zb[6]), "+v"(zb[7]),
                    "+v"(zb[8]), "+v"(zb[9]), "+v"(zb[10]), "+v"(zb[11]),
                    "+v"(zb[12]), "+v"(zb[13]), "+v"(zb[14]), "+v"(zb[15]));
  asm volatile("" : "+v"(zb[16]), "+v"(zb[17]), "+v"(zb[18]), "+v"(zb[19]),
                    "+v"(zb[20]), "+v"(zb[21]), "+v"(zb[22]), "+v"(zb[23]),
                    "+v"(zb[24]), "+v"(zb[25]), "+v"(zb[26]), "+v"(zb[27]),
                    "+v"(zb[28]), "+v"(zb[29]), "+v"(zb[30]), "+v"(zb[31]));

  float zna = 0.f, znb = 0.f;
#pragma unroll
  for (int j = 0; j < CDIM; ++j) zna = fmaf(za[j], za[j], zna);
#pragma unroll
  for (int j = 0; j < CDIM; ++j) znb = fmaf(zb[j], zb[j], znb);

  __syncthreads();

  float besta = FLT_MAX, bestb = FLT_MAX;
  int bia = kbeg, bib = kbeg;
#pragma unroll 4
  for (int k = 0; k < KCHUNK; ++k) {
    const float4* e4 = (const float4*)(se + k * CDIM);  // uniform -> broadcast
    float da = 0.f, db = 0.f;
#pragma unroll
    for (int j4 = 0; j4 < CDIM / 4; ++j4) {
      float4 e = e4[j4];
      da = fmaf(za[4 * j4 + 0], e.x, da);
      da = fmaf(za[4 * j4 + 1], e.y, da);
      da = fmaf(za[4 * j4 + 2], e.z, da);
      da = fmaf(za[4 * j4 + 3], e.w, da);
      db = fmaf(zb[4 * j4 + 0], e.x, db);
      db = fmaf(zb[4 * j4 + 1], e.y, db);
      db = fmaf(zb[4 * j4 + 2], e.z, db);
      db = fmaf(zb[4 * j4 + 3], e.w, db);
    }
    float en = sn[k];
    float sa = fmaf(-2.f, da, zna) + en;  // reference rounding grid
    float sb = fmaf(-2.f, db, znb) + en;
    if (sa < besta) { besta = sa; bia = kbeg + k; }  // strict <: first-min
    if (sb < bestb) { bestb = sb; bib = kbeg + k; }
  }

  unsigned long long ka =
      ((unsigned long long)__float_as_uint(besta) << 13) | (unsigned long long)bia;
  unsigned long long kb =
      ((unsigned long long)__float_as_uint(bestb) << 13) | (unsigned long long)bib;
  atomicMin(&key[r0], ka);
  atomicMin(&key[r1], kb);
}

// ---------------------------------------------------------------------------
// Kernel 3: idx from key; gather emb[idx] -> out; idx -> out; losses.
// ---------------------------------------------------------------------------
__global__ __launch_bounds__(256) void vq_finalize_kernel(
    const float* __restrict__ z, const float* __restrict__ emb,
    const unsigned long long* __restrict__ key, float* __restrict__ out) {
  const int r = blockIdx.x * 256 + threadIdx.x;
  const int bidx = (int)(key[r] & (unsigned long long)(KCODES - 1));

  const float4* q4 = (const float4*)(emb + (size_t)bidx * CDIM);
  const float4* z4 = (const float4*)(z + (size_t)r * CDIM);
  float4* o4 = (float4*)(out + OUT_Q + (size_t)r * CDIM);

  float lsum = 0.f;
#pragma unroll
  for (int j = 0; j < CDIM / 4; ++j) {
    float4 q = q4[j];
    float4 zz = z4[j];
    float dx = zz.x - q.x, dy = zz.y - q.y, dz = zz.z - q.z, dw = zz.w - q.w;
    lsum += dx * dx + dy * dy + dz * dz + dw * dw;
    o4[j] = q;  // forward straight-through output == quantized
  }
  out[OUT_IDX + r] = (float)bidx;

#pragma unroll
  for (int off = 32; off > 0; off >>= 1) lsum += __shfl_down(lsum, off, 64);
  if ((threadIdx.x & 63) == 0) {
    float v = lsum * (1.0f / (float)(NROW * CDIM));
    atomicAdd(out + OUT_LOSS + 0, v);  // vq_loss
    atomicAdd(out + OUT_LOSS + 1, v);  // commitment_loss (same fwd value)
  }
}

// ---------------------------------------------------------------------------
extern "C" void kernel_launch(void* const* d_in, const int* in_sizes, int n_in,
                              void* d_out, int out_size, void* d_ws,
                              size_t ws_size, hipStream_t stream) {
  const float* z = (const float*)d_in[0];    // 1048576 elems
  const float* emb = (const float*)d_in[1];  // 262144 elems
  float* out = (float*)d_out;

  // ws layout: enorm[8192] f32 (32KB) | key[32768] u64 (256KB)
  float* enorm = (float*)d_ws;
  unsigned long long* key = (unsigned long long*)(enorm + KCODES);

  vq_prep_kernel<<<NROW / 256, 256, 0, stream>>>(emb, enorm, key, out);
  vq_argmin_kernel<<<dim3(NROW / ROWS_PER_BLOCK, NCHUNK), 256, 0, stream>>>(
      z, emb, enorm, key);
  vq_finalize_kernel<<<NROW / 256, 256, 0, stream>>>(z, emb, key, out);
}

// Round 5
// 195.011 us; speedup vs baseline: 2.3896x; 1.4975x over previous
//
#include <hip/hip_runtime.h>
#include <cfloat>
#include <stdint.h>

// z: [32768, 32] fp32 rows; emb: [8192, 32] fp32 codes.
// Outputs (fp32, concat): quantized[1048576] | vq_loss | commit_loss | idx[32768]
//
// Strategy (R5): bf16 MFMA filter + exact fp32 re-check.
//  - sweep 1: per-row max of approx dot (bf16 MFMA, error <= ~2e-5 worst row)
//  - sweep 2: candidates = codes with dot~ >= rowmax~ - 1e-4 (sound margin)
//  - finalize: exact R4-identical fp32 chain on ~2-4 candidates/row.
#define NROW   32768
#define KCODES 8192
#define CDIM   32
#define OUT_Q    0
#define OUT_LOSS 1048576
#define OUT_IDX  1048578
#define HALF_EPS 1e-4f
#define MAXCAND  32

typedef short bf8_t __attribute__((ext_vector_type(8)));   // 8 bf16 (4 VGPRs)
typedef float f32x4 __attribute__((ext_vector_type(4)));

__device__ __forceinline__ unsigned short f2bf(float f) {  // RNE float->bf16
  unsigned int u = __float_as_uint(f);
  return (unsigned short)((u + 0x7FFFu + ((u >> 16) & 1u)) >> 16);
}
// Order-preserving float<->uint transform (for atomicMax on signed floats).
__device__ __forceinline__ unsigned int xf(float f) {
  unsigned int u = __float_as_uint(f);
  return u ^ (unsigned int)(((int)u >> 31) | 0x80000000);
}
__device__ __forceinline__ float unxf(unsigned int k) {
  unsigned int u = (k & 0x80000000u) ? (k ^ 0x80000000u) : ~k;
  return __uint_as_float(u);
}

// ---------------------------------------------------------------------------
// Prep: z/emb -> bf16 copies; enorm (bit-identical to R4 chain); init
// mmax/ccnt/losses.  grid 128x256 = 32768 threads.
// ---------------------------------------------------------------------------
__global__ __launch_bounds__(256) void vq_prep(
    const float* __restrict__ z, const float* __restrict__ emb,
    unsigned short* __restrict__ zh, unsigned short* __restrict__ eh,
    float* __restrict__ enorm, unsigned int* __restrict__ mmax,
    int* __restrict__ ccnt, float* __restrict__ out) {
  const int t = blockIdx.x * 256 + threadIdx.x;  // 0..32767
  {
    const float4* z4 = (const float4*)(z + (size_t)t * CDIM);
    unsigned int w[16];
#pragma unroll
    for (int j = 0; j < 8; ++j) {
      float4 v = z4[j];
      w[2 * j]     = (unsigned int)f2bf(v.x) | ((unsigned int)f2bf(v.y) << 16);
      w[2 * j + 1] = (unsigned int)f2bf(v.z) | ((unsigned int)f2bf(v.w) << 16);
    }
    uint4* o = (uint4*)(zh + (size_t)t * CDIM);
#pragma unroll
    for (int j = 0; j < 4; ++j)
      o[j] = make_uint4(w[4 * j], w[4 * j + 1], w[4 * j + 2], w[4 * j + 3]);
  }
  if (t < KCODES) {
    const float4* e4 = (const float4*)(emb + (size_t)t * CDIM);
    float s = 0.f;
    unsigned int w[16];
#pragma unroll
    for (int j = 0; j < 8; ++j) {
      float4 v = e4[j];
      s += v.x * v.x + v.y * v.y + v.z * v.z + v.w * v.w;  // R4 enorm chain
      w[2 * j]     = (unsigned int)f2bf(v.x) | ((unsigned int)f2bf(v.y) << 16);
      w[2 * j + 1] = (unsigned int)f2bf(v.z) | ((unsigned int)f2bf(v.w) << 16);
    }
    enorm[t] = s;
    uint4* o = (uint4*)(eh + (size_t)t * CDIM);
#pragma unroll
    for (int j = 0; j < 4; ++j)
      o[j] = make_uint4(w[4 * j], w[4 * j + 1], w[4 * j + 2], w[4 * j + 3]);
  }
  mmax[t] = 0u;   // transformed -inf
  ccnt[t] = 0;
  if (t < 2) out[OUT_LOSS + t] = 0.f;
}

// ---------------------------------------------------------------------------
// Sweep 1: per-row max of dot~ via MFMA. Block = 4 waves, all on the same
// 32 rows; wave w covers code quarter w (2048 codes = 128 tiles of 16).
// A-frag: A[m=lane&15][k=quad*8+j] = zh[row][k]  (16B contiguous load)
// B-frag: B[k][n=lane&15] = eh[code][k]          (16B contiguous load)
// C/D:    lane holds D[row=quad*4+i][col=lane&15], i=0..3.
// grid = 1024 blocks.
// ---------------------------------------------------------------------------
__global__ __launch_bounds__(256, 4) void vq_sweep_max(
    const unsigned short* __restrict__ zh, const unsigned short* __restrict__ eh,
    unsigned int* __restrict__ mmax) {
  const int wid = threadIdx.x >> 6, lane = threadIdx.x & 63;
  const int quad = lane >> 4, col = lane & 15;
  const int rbase = blockIdx.x * 32;
  const int kbase = wid * 2048;

  bf8_t a0 = *(const bf8_t*)(zh + (size_t)(rbase + col) * CDIM + quad * 8);
  bf8_t a1 = *(const bf8_t*)(zh + (size_t)(rbase + 16 + col) * CDIM + quad * 8);

  float mx0[4], mx1[4];
#pragma unroll
  for (int i = 0; i < 4; ++i) { mx0[i] = -FLT_MAX; mx1[i] = -FLT_MAX; }

  const bf8_t* ep = (const bf8_t*)(eh + ((size_t)kbase + col) * CDIM + quad * 8);
#pragma unroll 4
  for (int t = 0; t < 128; ++t) {
    bf8_t b = ep[(size_t)t * 64];  // +16 codes * 64B per tile
    f32x4 d0 = __builtin_amdgcn_mfma_f32_16x16x32_bf16(
        a0, b, (f32x4){0.f, 0.f, 0.f, 0.f}, 0, 0, 0);
    f32x4 d1 = __builtin_amdgcn_mfma_f32_16x16x32_bf16(
        a1, b, (f32x4){0.f, 0.f, 0.f, 0.f}, 0, 0, 0);
#pragma unroll
    for (int i = 0; i < 4; ++i) {
      mx0[i] = fmaxf(mx0[i], d0[i]);
      mx1[i] = fmaxf(mx1[i], d1[i]);
    }
  }
  // reduce over the 16 cols (lanes with same quad)
#pragma unroll
  for (int off = 1; off < 16; off <<= 1) {
#pragma unroll
    for (int i = 0; i < 4; ++i) {
      mx0[i] = fmaxf(mx0[i], __shfl_xor(mx0[i], off, 64));
      mx1[i] = fmaxf(mx1[i], __shfl_xor(mx1[i], off, 64));
    }
  }
  if (col == 0) {
#pragma unroll
    for (int i = 0; i < 4; ++i) {
      atomicMax(&mmax[rbase + quad * 4 + i], xf(mx0[i]));
      atomicMax(&mmax[rbase + 16 + quad * 4 + i], xf(mx1[i]));
    }
  }
}

// ---------------------------------------------------------------------------
// Sweep 2: identical MFMA recompute (bitwise-same dot~); emit candidates
// where dot~ >= rowmax~ - HALF_EPS into per-row slots. The rowmax achiever
// always passes (same bits) -> every row gets >= 1 candidate.
// ---------------------------------------------------------------------------
__global__ __launch_bounds__(256, 4) void vq_sweep_cand(
    const unsigned short* __restrict__ zh, const unsigned short* __restrict__ eh,
    const unsigned int* __restrict__ mmax, int* __restrict__ ccnt,
    int* __restrict__ cand) {
  const int wid = threadIdx.x >> 6, lane = threadIdx.x & 63;
  const int quad = lane >> 4, col = lane & 15;
  const int rbase = blockIdx.x * 32;
  const int kbase = wid * 2048;

  bf8_t a0 = *(const bf8_t*)(zh + (size_t)(rbase + col) * CDIM + quad * 8);
  bf8_t a1 = *(const bf8_t*)(zh + (size_t)(rbase + 16 + col) * CDIM + quad * 8);

  float th0[4], th1[4];
#pragma unroll
  for (int i = 0; i < 4; ++i) {
    th0[i] = unxf(mmax[rbase + quad * 4 + i]) - HALF_EPS;
    th1[i] = unxf(mmax[rbase + 16 + quad * 4 + i]) - HALF_EPS;
  }

  const bf8_t* ep = (const bf8_t*)(eh + ((size_t)kbase + col) * CDIM + quad * 8);
#pragma unroll 2
  for (int t = 0; t < 128; ++t) {
    bf8_t b = ep[(size_t)t * 64];
    f32x4 d0 = __builtin_amdgcn_mfma_f32_16x16x32_bf16(
        a0, b, (f32x4){0.f, 0.f, 0.f, 0.f}, 0, 0, 0);
    f32x4 d1 = __builtin_amdgcn_mfma_f32_16x16x32_bf16(
        a1, b, (f32x4){0.f, 0.f, 0.f, 0.f}, 0, 0, 0);
    const int code = kbase + t * 16 + col;
#pragma unroll
    for (int i = 0; i < 4; ++i) {
      if (d0[i] >= th0[i]) {
        int r = rbase + quad * 4 + i;
        int s = atomicAdd(&ccnt[r], 1);
        if (s < MAXCAND) cand[(size_t)r * MAXCAND + s] = code;
      }
      if (d1[i] >= th1[i]) {
        int r = rbase + 16 + quad * 4 + i;
        int s = atomicAdd(&ccnt[r], 1);
        if (s < MAXCAND) cand[(size_t)r * MAXCAND + s] = code;
      }
    }
  }
}

// ---------------------------------------------------------------------------
// Finalize: one thread per row. Exact fp32 re-eval of candidates with the
// R4-passing bit-identical chain; overflow (>MAXCAND, never expected) falls
// back to a full exact scan. Then gather, idx, losses.
// ---------------------------------------------------------------------------
__global__ __launch_bounds__(256) void vq_final(
    const float* __restrict__ z, const float* __restrict__ emb,
    const float* __restrict__ enorm, const int* __restrict__ ccnt,
    const int* __restrict__ cand, float* __restrict__ out) {
  const int r = blockIdx.x * 256 + threadIdx.x;

  float zr[CDIM];
  const float4* z4 = (const float4*)(z + (size_t)r * CDIM);
#pragma unroll
  for (int j = 0; j < 8; ++j) {
    float4 v = z4[j];
    zr[4 * j + 0] = v.x; zr[4 * j + 1] = v.y;
    zr[4 * j + 2] = v.z; zr[4 * j + 3] = v.w;
  }
  float znorm = 0.f;
#pragma unroll
  for (int j = 0; j < CDIM; ++j) znorm = fmaf(zr[j], zr[j], znorm);

  const int n = ccnt[r];
  float best = FLT_MAX;
  int bidx = KCODES;
  if (n <= MAXCAND) {
    for (int j = 0; j < n; ++j) {
      int k = cand[(size_t)r * MAXCAND + j];
      const float* ek = emb + (size_t)k * CDIM;
      float dot = 0.f;
#pragma unroll
      for (int q = 0; q < CDIM; ++q) dot = fmaf(zr[q], ek[q], dot);
      float s = fmaf(-2.f, dot, znorm) + enorm[k];
      if (s < best || (s == best && k < bidx)) { best = s; bidx = k; }
    }
  } else {  // safety net: exact full scan, ascending k, strict <
    for (int k = 0; k < KCODES; ++k) {
      const float* ek = emb + (size_t)k * CDIM;
      float dot = 0.f;
#pragma unroll
      for (int q = 0; q < CDIM; ++q) dot = fmaf(zr[q], ek[q], dot);
      float s = fmaf(-2.f, dot, znorm) + enorm[k];
      if (s < best) { best = s; bidx = k; }
    }
  }

  const float4* q4 = (const float4*)(emb + (size_t)bidx * CDIM);
  float4* o4 = (float4*)(out + OUT_Q + (size_t)r * CDIM);
  float lsum = 0.f;
#pragma unroll
  for (int j = 0; j < 8; ++j) {
    float4 q = q4[j];
    float dx = zr[4 * j + 0] - q.x, dy = zr[4 * j + 1] - q.y;
    float dz = zr[4 * j + 2] - q.z, dw = zr[4 * j + 3] - q.w;
    lsum += dx * dx + dy * dy + dz * dz + dw * dw;
    o4[j] = q;
  }
  out[OUT_IDX + r] = (float)bidx;

#pragma unroll
  for (int off = 32; off > 0; off >>= 1) lsum += __shfl_down(lsum, off, 64);
  if ((threadIdx.x & 63) == 0) {
    float v = lsum * (1.0f / (float)(NROW * CDIM));
    atomicAdd(out + OUT_LOSS + 0, v);
    atomicAdd(out + OUT_LOSS + 1, v);
  }
}

// ---------------------------------------------------------------------------
extern "C" void kernel_launch(void* const* d_in, const int* in_sizes, int n_in,
                              void* d_out, int out_size, void* d_ws,
                              size_t ws_size, hipStream_t stream) {
  const float* z = (const float*)d_in[0];
  const float* emb = (const float*)d_in[1];
  float* out = (float*)d_out;

  // ws: enorm 32KB | zh 2MB | eh 512KB | mmax 128KB | ccnt 128KB | cand 4MB
  float* enorm = (float*)d_ws;
  unsigned short* zh = (unsigned short*)(enorm + KCODES);
  unsigned short* eh = zh + (size_t)NROW * CDIM;
  unsigned int* mmax = (unsigned int*)(eh + (size_t)KCODES * CDIM);
  int* ccnt = (int*)(mmax + NROW);
  int* cand = ccnt + NROW;

  vq_prep<<<NROW / 256, 256, 0, stream>>>(z, emb, zh, eh, enorm, mmax, ccnt, out);
  vq_sweep_max<<<NROW / 32, 256, 0, stream>>>(zh, eh, mmax);
  vq_sweep_cand<<<NROW / 32, 256, 0, stream>>>(zh, eh, mmax, ccnt, cand);
  vq_final<<<NROW / 256, 256, 0, stream>>>(z, emb, enorm, ccnt, cand, out);
}